// Round 7
// baseline (62.649 us; speedup 1.0000x reference)
//
#include <hip/hip_runtime.h>
#include <hip/hip_bf16.h>
#include <stdint.h>

// Mahalanobis: out[i] = delta_i @ S_inv @ delta_i^T, delta = x - x_fit
// N=65536, D=256.
// Round 6 -> 7: (1) 32-row tiles (NT=4, 512 blocks x 128 rows) halve the
// staging-prefetch registers (32 VGPR) so the block fits the 128-unified-reg
// budget -> 2 blocks/CU (TLP) *and* the cross-barrier prefetch pipeline.
// Round 2 (TLP only) and round 6 (pipeline only) both hit ~4 TB/s effective;
// this combines them. (2) S_inv f32->bf16 conversion fused into the main
// kernel (each wave converts its own 32-row slice from L2 once per block) -
// the serial prep_S launch (~4-6us of 35.9) is gone.

#define D 256
#define BLOCK_T 512           // 8 waves
#define ROWS_PER_TILE 32
#define NT 4                  // 128 rows/block; grid = 65536/128 = 512
#define LDS_STRIDE 272

typedef __attribute__((ext_vector_type(4))) float f32x4;
typedef __attribute__((ext_vector_type(8))) short bf16x8;
typedef __attribute__((ext_vector_type(4))) short bf16x4;

static __device__ __forceinline__ unsigned short f2bf(float f) {
    union { float f; uint32_t u; } v; v.f = f;
    uint32_t u = v.u;
    return (unsigned short)((u + 0x7FFFu + ((u >> 16) & 1u)) >> 16);
}
static __device__ __forceinline__ float bf2f(unsigned short s) {
    union { uint32_t u; float f; } v; v.u = ((uint32_t)s) << 16;
    return v.f;
}
static __device__ __forceinline__ bf16x8 cvt8(f32x4 lo, f32x4 hi) {
    bf16x8 o;
    o[0] = (short)f2bf(lo[0]); o[1] = (short)f2bf(lo[1]);
    o[2] = (short)f2bf(lo[2]); o[3] = (short)f2bf(lo[3]);
    o[4] = (short)f2bf(hi[0]); o[5] = (short)f2bf(hi[1]);
    o[6] = (short)f2bf(hi[2]); o[7] = (short)f2bf(hi[3]);
    return o;
}

// Opaque 16B global load: fixed issue point (cannot be sunk to its use).
static __device__ __forceinline__ f32x4 gload4f(const float* p) {
    f32x4 r;
    asm volatile("global_load_dwordx4 %0, %1, off" : "=v"(r) : "v"(p));
    return r;
}

__global__ __launch_bounds__(BLOCK_T, 4) void mahal_kernel(
    const float* __restrict__ x, const float* __restrict__ xf,
    const float* __restrict__ S, float* __restrict__ out)
{
    __shared__ unsigned short ld[ROWS_PER_TILE * LDS_STRIDE]; // 17408 B
    __shared__ float psum[8 * ROWS_PER_TILE];                 // 1024 B

    const int t    = threadIdx.x;
    const int w    = t >> 6;      // wave 0..7: owns S cols [w*32, w*32+32)
    const int lane = t & 63;
    const int lo4  = lane & 15;
    const int kg   = lane >> 4;   // k-group 0..3
    const int lrow0 = t >> 5;          // staging: 0..15
    const int col   = (t & 31) * 8;    // staging: 0..248
    const int blockRow0 = blockIdx.x * (NT * ROWS_PER_TILE);

    // ---- S fragments (fused f32->bf16, from L2, once per block).
    // Used as the MFMA *A*-operand: A[i][k] = S[w*32 + nb*16 + i][k].
    // Loop-invariant -> compiler parks the bf16 frags in AGPRs.
    bf16x8 b0[8], b1[8];
    {
        const float* Sp = S + (w * 32 + lo4) * D + kg * 8;
        #pragma unroll
        for (int kb = 0; kb < 8; ++kb) {
            f32x4 l0 = *(const f32x4*)(Sp + kb * 32);
            f32x4 h0 = *(const f32x4*)(Sp + kb * 32 + 4);
            b0[kb] = cvt8(l0, h0);
            f32x4 l1 = *(const f32x4*)(Sp + 16 * D + kb * 32);
            f32x4 h1 = *(const f32x4*)(Sp + 16 * D + kb * 32 + 4);
            b1[kb] = cvt8(l1, h1);
        }
    }

    // ---- prologue: issue tile 0 staging loads (8 x 16B per thread) ----
    f32x4 xa[2], xb[2], fa[2], fb[2];
    #pragma unroll
    for (int i = 0; i < 2; ++i) {
        const int g = (blockRow0 + i * 16 + lrow0) * D + col;
        xa[i] = gload4f(x + g);
        xb[i] = gload4f(x + g + 4);
        fa[i] = gload4f(xf + g);
        fb[i] = gload4f(xf + g + 4);
    }

    for (int j = 0; j < NT; ++j) {
        // tile j's staged registers arrived (asm loads: we own the wait)
        asm volatile("s_waitcnt vmcnt(0)" ::: "memory");
        __builtin_amdgcn_sched_barrier(0);

        if (j > 0) {
            // all waves done with tile j-1 (LDS reads + psum writes retired)
            asm volatile("s_waitcnt lgkmcnt(0)" ::: "memory");
            __builtin_amdgcn_s_barrier();
            // combine tile j-1 partials (wave 0) while others convert
            if (t < ROWS_PER_TILE) {
                float s = 0.f;
                #pragma unroll
                for (int ww = 0; ww < 8; ++ww) s += psum[ww * ROWS_PER_TILE + t];
                out[blockRow0 + (j - 1) * ROWS_PER_TILE + t] = s;
            }
        }

        // ---- convert tile j -> bf16 delta in LDS ----
        #pragma unroll
        for (int i = 0; i < 2; ++i) {
            bf16x8 o;
            o[0] = (short)f2bf(xa[i][0] - fa[i][0]);
            o[1] = (short)f2bf(xa[i][1] - fa[i][1]);
            o[2] = (short)f2bf(xa[i][2] - fa[i][2]);
            o[3] = (short)f2bf(xa[i][3] - fa[i][3]);
            o[4] = (short)f2bf(xb[i][0] - fb[i][0]);
            o[5] = (short)f2bf(xb[i][1] - fb[i][1]);
            o[6] = (short)f2bf(xb[i][2] - fb[i][2]);
            o[7] = (short)f2bf(xb[i][3] - fb[i][3]);
            *(bf16x8*)(&ld[(i * 16 + lrow0) * LDS_STRIDE + col]) = o;
        }

        // ---- issue tile j+1 loads: fly across the barrier, under compute ----
        if (j + 1 < NT) {
            #pragma unroll
            for (int i = 0; i < 2; ++i) {
                const int g = (blockRow0 + (j + 1) * ROWS_PER_TILE + i * 16 + lrow0) * D + col;
                xa[i] = gload4f(x + g);
                xb[i] = gload4f(x + g + 4);
                fa[i] = gload4f(xf + g);
                fb[i] = gload4f(xf + g + 4);
            }
        }

        // LDS writes visible; lgkmcnt only - prefetch stays in flight
        asm volatile("s_waitcnt lgkmcnt(0)" ::: "memory");
        __builtin_amdgcn_s_barrier();
        __builtin_amdgcn_sched_barrier(0);

        // ---- compute tile j: acc = T^T for this wave's col slice ----
        #pragma unroll
        for (int rt = 0; rt < 2; ++rt) {
            f32x4 acc0 = (f32x4){0.f, 0.f, 0.f, 0.f};
            f32x4 acc1 = (f32x4){0.f, 0.f, 0.f, 0.f};
            const unsigned short* A = &ld[(rt * 16 + lo4) * LDS_STRIDE + kg * 8];
            #pragma unroll
            for (int kb = 0; kb < 8; ++kb) {
                bf16x8 a = *(const bf16x8*)(A + kb * 32);
                // swapped operands: D[i][j] = sum_k S[slice_i][k] * delta[row_j][k]
                acc0 = __builtin_amdgcn_mfma_f32_16x16x32_bf16(b0[kb], a, acc0, 0, 0, 0);
                acc1 = __builtin_amdgcn_mfma_f32_16x16x32_bf16(b1[kb], a, acc1, 0, 0, 0);
            }
            // lane lo4 = delta row (rt*16+lo4); reg r of acc_nb holds
            // T[drow][w*32 + nb*16 + kg*4 + r] -> dot with delta at those cols
            const unsigned short* dr = &ld[(rt * 16 + lo4) * LDS_STRIDE + w * 32 + kg * 4];
            bf16x4 d0 = *(const bf16x4*)(dr);
            bf16x4 d1 = *(const bf16x4*)(dr + 16);
            float pr = 0.f;
            #pragma unroll
            for (int r = 0; r < 4; ++r) {
                pr += acc0[r] * bf2f((unsigned short)d0[r]);
                pr += acc1[r] * bf2f((unsigned short)d1[r]);
            }
            // reduce over the 4 k-groups holding the same delta row
            pr += __shfl_xor(pr, 16, 64);
            pr += __shfl_xor(pr, 32, 64);
            if (lane < 16)
                psum[w * ROWS_PER_TILE + rt * 16 + lane] = pr;
        }
    }

    // ---- final tile's combine ----
    asm volatile("s_waitcnt lgkmcnt(0)" ::: "memory");
    __builtin_amdgcn_s_barrier();
    if (t < ROWS_PER_TILE) {
        float s = 0.f;
        #pragma unroll
        for (int ww = 0; ww < 8; ++ww) s += psum[ww * ROWS_PER_TILE + t];
        out[blockRow0 + (NT - 1) * ROWS_PER_TILE + t] = s;
    }
}

extern "C" void kernel_launch(void* const* d_in, const int* in_sizes, int n_in,
                              void* d_out, int out_size, void* d_ws, size_t ws_size,
                              hipStream_t stream) {
    const float* x  = (const float*)d_in[0];
    const float* xf = (const float*)d_in[1];
    const float* S  = (const float*)d_in[2];
    float* out = (float*)d_out;

    const int nRows = in_sizes[0] / D;                      // 65536
    const int nBlocks = nRows / (NT * ROWS_PER_TILE);       // 512
    mahal_kernel<<<nBlocks, BLOCK_T, 0, stream>>>(x, xf, S, out);
}

// Round 8
// 34.143 us; speedup vs baseline: 1.8349x; 1.8349x over previous
//
#include <hip/hip_runtime.h>
#include <hip/hip_bf16.h>
#include <stdint.h>

// Mahalanobis: out[i] = delta_i @ S_inv @ delta_i^T, delta = x - x_fit
// N=65536, D=256.
// Round 7 -> 8: round 7's WRITE_SIZE=84MB exposed scratch spills - the fused
// f32 S-conversion temps + 64 S-frags + 32 staging regs overflowed the
// 128-unified-reg cap of __launch_bounds__(512,4). Fix: restore the prep_S
// kernel (S pre-converted to bf16; plain loads -> AGPRs, no f32 temps) and
// keep the rest of round 7: 32-row tiles, NT=4, 512 blocks -> 2 blocks/CU
// (TLP) AND the cross-barrier prefetch pipeline (loads never drained by the
// barrier). Budget: 32 staging + 64 S(AGPR) + ~25 misc ~= 120 <= 128.

#define D 256
#define BLOCK_T 512           // 8 waves
#define ROWS_PER_TILE 32
#define NT 4                  // 128 rows/block; grid = 65536/128 = 512
#define LDS_STRIDE 272

typedef __attribute__((ext_vector_type(4))) float f32x4;
typedef __attribute__((ext_vector_type(8))) short bf16x8;
typedef __attribute__((ext_vector_type(4))) short bf16x4;

static __device__ __forceinline__ unsigned short f2bf(float f) {
    union { float f; uint32_t u; } v; v.f = f;
    uint32_t u = v.u;
    return (unsigned short)((u + 0x7FFFu + ((u >> 16) & 1u)) >> 16);
}
static __device__ __forceinline__ float bf2f(unsigned short s) {
    union { uint32_t u; float f; } v; v.u = ((uint32_t)s) << 16;
    return v.f;
}

// Opaque 16B global load: fixed issue point (cannot be sunk to its use).
static __device__ __forceinline__ f32x4 gload4f(const float* p) {
    f32x4 r;
    asm volatile("global_load_dwordx4 %0, %1, off" : "=v"(r) : "v"(p));
    return r;
}

// S_inv fp32 -> bf16 (row-major; S is symmetric so this is also S^T)
__global__ void prep_S_kernel(const float* __restrict__ S, unsigned short* __restrict__ Sb) {
    int i = (blockIdx.x * 256 + threadIdx.x) * 4;
    f32x4 v = *(const f32x4*)(S + i);
    uint32_t lo = (uint32_t)f2bf(v[0]) | ((uint32_t)f2bf(v[1]) << 16);
    uint32_t hi = (uint32_t)f2bf(v[2]) | ((uint32_t)f2bf(v[3]) << 16);
    *(uint2*)(Sb + i) = make_uint2(lo, hi);
}

__global__ __launch_bounds__(BLOCK_T, 4) void mahal_kernel(
    const float* __restrict__ x, const float* __restrict__ xf,
    const unsigned short* __restrict__ Sb, float* __restrict__ out)
{
    __shared__ unsigned short ld[ROWS_PER_TILE * LDS_STRIDE]; // 17408 B
    __shared__ float psum[8 * ROWS_PER_TILE];                 // 1024 B

    const int t    = threadIdx.x;
    const int w    = t >> 6;      // wave 0..7: owns S cols [w*32, w*32+32)
    const int lane = t & 63;
    const int lo4  = lane & 15;
    const int kg   = lane >> 4;   // k-group 0..3
    const int lrow0 = t >> 5;          // staging: 0..15
    const int col   = (t & 31) * 8;    // staging: 0..248
    const int blockRow0 = blockIdx.x * (NT * ROWS_PER_TILE);

    // ---- S fragments: bf16 plain loads -> compiler parks them in AGPRs
    // (observed rounds 2-4). A-operand: A[i][k] = S[w*32 + nb*16 + i][k].
    bf16x8 b0[8], b1[8];
    {
        const unsigned short* Sp = Sb + (w * 32 + lo4) * D + kg * 8;
        #pragma unroll
        for (int kb = 0; kb < 8; ++kb) {
            b0[kb] = *(const bf16x8*)(Sp + kb * 32);
            b1[kb] = *(const bf16x8*)(Sp + 16 * D + kb * 32);
        }
    }

    // ---- prologue: issue tile 0 staging loads (8 x 16B per thread) ----
    f32x4 xa[2], xb[2], fa[2], fb[2];
    #pragma unroll
    for (int i = 0; i < 2; ++i) {
        const int g = (blockRow0 + i * 16 + lrow0) * D + col;
        xa[i] = gload4f(x + g);
        xb[i] = gload4f(x + g + 4);
        fa[i] = gload4f(xf + g);
        fb[i] = gload4f(xf + g + 4);
    }

    for (int j = 0; j < NT; ++j) {
        // tile j's staged registers arrived (asm loads: we own the wait)
        asm volatile("s_waitcnt vmcnt(0)" ::: "memory");
        __builtin_amdgcn_sched_barrier(0);

        if (j > 0) {
            // all waves done with tile j-1 (LDS reads + psum writes retired)
            asm volatile("s_waitcnt lgkmcnt(0)" ::: "memory");
            __builtin_amdgcn_s_barrier();
            // combine tile j-1 partials (wave 0) while others convert
            if (t < ROWS_PER_TILE) {
                float s = 0.f;
                #pragma unroll
                for (int ww = 0; ww < 8; ++ww) s += psum[ww * ROWS_PER_TILE + t];
                out[blockRow0 + (j - 1) * ROWS_PER_TILE + t] = s;
            }
        }

        // ---- convert tile j -> bf16 delta in LDS ----
        #pragma unroll
        for (int i = 0; i < 2; ++i) {
            bf16x8 o;
            o[0] = (short)f2bf(xa[i][0] - fa[i][0]);
            o[1] = (short)f2bf(xa[i][1] - fa[i][1]);
            o[2] = (short)f2bf(xa[i][2] - fa[i][2]);
            o[3] = (short)f2bf(xa[i][3] - fa[i][3]);
            o[4] = (short)f2bf(xb[i][0] - fb[i][0]);
            o[5] = (short)f2bf(xb[i][1] - fb[i][1]);
            o[6] = (short)f2bf(xb[i][2] - fb[i][2]);
            o[7] = (short)f2bf(xb[i][3] - fb[i][3]);
            *(bf16x8*)(&ld[(i * 16 + lrow0) * LDS_STRIDE + col]) = o;
        }

        // ---- issue tile j+1 loads: fly across the barrier, under compute ----
        if (j + 1 < NT) {
            #pragma unroll
            for (int i = 0; i < 2; ++i) {
                const int g = (blockRow0 + (j + 1) * ROWS_PER_TILE + i * 16 + lrow0) * D + col;
                xa[i] = gload4f(x + g);
                xb[i] = gload4f(x + g + 4);
                fa[i] = gload4f(xf + g);
                fb[i] = gload4f(xf + g + 4);
            }
        }

        // LDS writes visible; lgkmcnt only - prefetch stays in flight
        asm volatile("s_waitcnt lgkmcnt(0)" ::: "memory");
        __builtin_amdgcn_s_barrier();
        __builtin_amdgcn_sched_barrier(0);

        // ---- compute tile j: acc = T^T for this wave's col slice ----
        #pragma unroll
        for (int rt = 0; rt < 2; ++rt) {
            f32x4 acc0 = (f32x4){0.f, 0.f, 0.f, 0.f};
            f32x4 acc1 = (f32x4){0.f, 0.f, 0.f, 0.f};
            const unsigned short* A = &ld[(rt * 16 + lo4) * LDS_STRIDE + kg * 8];
            #pragma unroll
            for (int kb = 0; kb < 8; ++kb) {
                bf16x8 a = *(const bf16x8*)(A + kb * 32);
                // swapped operands: D[i][j] = sum_k S[slice_i][k] * delta[row_j][k]
                acc0 = __builtin_amdgcn_mfma_f32_16x16x32_bf16(b0[kb], a, acc0, 0, 0, 0);
                acc1 = __builtin_amdgcn_mfma_f32_16x16x32_bf16(b1[kb], a, acc1, 0, 0, 0);
            }
            // lane lo4 = delta row (rt*16+lo4); reg r of acc_nb holds
            // T[drow][w*32 + nb*16 + kg*4 + r] -> dot with delta at those cols
            const unsigned short* dr = &ld[(rt * 16 + lo4) * LDS_STRIDE + w * 32 + kg * 4];
            bf16x4 d0 = *(const bf16x4*)(dr);
            bf16x4 d1 = *(const bf16x4*)(dr + 16);
            float pr = 0.f;
            #pragma unroll
            for (int r = 0; r < 4; ++r) {
                pr += acc0[r] * bf2f((unsigned short)d0[r]);
                pr += acc1[r] * bf2f((unsigned short)d1[r]);
            }
            // reduce over the 4 k-groups holding the same delta row
            pr += __shfl_xor(pr, 16, 64);
            pr += __shfl_xor(pr, 32, 64);
            if (lane < 16)
                psum[w * ROWS_PER_TILE + rt * 16 + lane] = pr;
        }
    }

    // ---- final tile's combine ----
    asm volatile("s_waitcnt lgkmcnt(0)" ::: "memory");
    __builtin_amdgcn_s_barrier();
    if (t < ROWS_PER_TILE) {
        float s = 0.f;
        #pragma unroll
        for (int ww = 0; ww < 8; ++ww) s += psum[ww * ROWS_PER_TILE + t];
        out[blockRow0 + (NT - 1) * ROWS_PER_TILE + t] = s;
    }
}

extern "C" void kernel_launch(void* const* d_in, const int* in_sizes, int n_in,
                              void* d_out, int out_size, void* d_ws, size_t ws_size,
                              hipStream_t stream) {
    const float* x  = (const float*)d_in[0];
    const float* xf = (const float*)d_in[1];
    const float* S  = (const float*)d_in[2];
    float* out = (float*)d_out;
    unsigned short* Sb = (unsigned short*)d_ws;  // 65536 * 2B = 128 KB scratch

    prep_S_kernel<<<(D * D) / (256 * 4), 256, 0, stream>>>(S, Sb);

    const int nRows = in_sizes[0] / D;                      // 65536
    const int nBlocks = nRows / (NT * ROWS_PER_TILE);       // 512
    mahal_kernel<<<nBlocks, BLOCK_T, 0, stream>>>(x, xf, Sb, out);
}

// Round 9
// 34.091 us; speedup vs baseline: 1.8377x; 1.0015x over previous
//
#include <hip/hip_runtime.h>
#include <hip/hip_bf16.h>
#include <stdint.h>

// Mahalanobis: out[i] = delta_i @ S_inv @ delta_i^T, delta = x - x_fit
// N=65536, D=256.
// Round 8 -> 9: COALESCING FIX. Since round 0 every staging load used
// col=(t&31)*8: each 16B load strided 32B across lanes -> every instruction
// touched 16 cache lines for 512B payload (2x line-requests per byte). This
// explains the universal ~3.5 TB/s effective-read ceiling across all seven
// prior structures. Now wave w owns tile-rows w*4..w*4+3 and each load is
// 64 lanes x 16B = 1KB CONTIGUOUS (lane l -> floats l*4..l*4+3 of one row).
// Everything else identical to round 8 (2 blocks/CU TLP + cross-barrier
// prefetch pipeline, S bf16 in AGPRs, swapped-MFMA epilogue).

#define D 256
#define BLOCK_T 512           // 8 waves
#define ROWS_PER_TILE 32
#define NT 4                  // 128 rows/block; grid = 65536/128 = 512
#define LDS_STRIDE 272

typedef __attribute__((ext_vector_type(4))) float f32x4;
typedef __attribute__((ext_vector_type(8))) short bf16x8;
typedef __attribute__((ext_vector_type(4))) short bf16x4;

static __device__ __forceinline__ unsigned short f2bf(float f) {
    union { float f; uint32_t u; } v; v.f = f;
    uint32_t u = v.u;
    return (unsigned short)((u + 0x7FFFu + ((u >> 16) & 1u)) >> 16);
}
static __device__ __forceinline__ float bf2f(unsigned short s) {
    union { uint32_t u; float f; } v; v.u = ((uint32_t)s) << 16;
    return v.f;
}

// Opaque 16B global load: fixed issue point (cannot be sunk to its use).
static __device__ __forceinline__ f32x4 gload4f(const float* p) {
    f32x4 r;
    asm volatile("global_load_dwordx4 %0, %1, off" : "=v"(r) : "v"(p));
    return r;
}

// S_inv fp32 -> bf16 (row-major; S is symmetric so this is also S^T)
__global__ void prep_S_kernel(const float* __restrict__ S, unsigned short* __restrict__ Sb) {
    int i = (blockIdx.x * 256 + threadIdx.x) * 4;
    f32x4 v = *(const f32x4*)(S + i);
    uint32_t lo = (uint32_t)f2bf(v[0]) | ((uint32_t)f2bf(v[1]) << 16);
    uint32_t hi = (uint32_t)f2bf(v[2]) | ((uint32_t)f2bf(v[3]) << 16);
    *(uint2*)(Sb + i) = make_uint2(lo, hi);
}

__global__ __launch_bounds__(BLOCK_T, 4) void mahal_kernel(
    const float* __restrict__ x, const float* __restrict__ xf,
    const unsigned short* __restrict__ Sb, float* __restrict__ out)
{
    __shared__ unsigned short ld[ROWS_PER_TILE * LDS_STRIDE]; // 17408 B
    __shared__ float psum[8 * ROWS_PER_TILE];                 // 1024 B

    const int t    = threadIdx.x;
    const int w    = t >> 6;      // wave 0..7: owns S cols [w*32, w*32+32)
    const int lane = t & 63;
    const int lo4  = lane & 15;
    const int kg   = lane >> 4;   // k-group 0..3
    const int srow = w << 2;      // staging: wave's 4 tile-rows
    const int lx4  = lane * 4;    // staging: lane's 4 floats (CONTIGUOUS)
    const int blockRow0 = blockIdx.x * (NT * ROWS_PER_TILE);

    // ---- S fragments: bf16 plain loads -> compiler parks them in AGPRs.
    // A-operand: A[i][k] = S[w*32 + nb*16 + i][k].
    bf16x8 b0[8], b1[8];
    {
        const unsigned short* Sp = Sb + (w * 32 + lo4) * D + kg * 8;
        #pragma unroll
        for (int kb = 0; kb < 8; ++kb) {
            b0[kb] = *(const bf16x8*)(Sp + kb * 32);
            b1[kb] = *(const bf16x8*)(Sp + 16 * D + kb * 32);
        }
    }

    // ---- prologue: issue tile 0 staging loads (8 x 1KB-contiguous) ----
    f32x4 xs[4], fs[4];
    #pragma unroll
    for (int q = 0; q < 4; ++q) {
        const int g = (blockRow0 + srow + q) * D + lx4;
        xs[q] = gload4f(x + g);
        fs[q] = gload4f(xf + g);
    }

    for (int j = 0; j < NT; ++j) {
        // tile j's staged registers arrived (asm loads: we own the wait)
        asm volatile("s_waitcnt vmcnt(0)" ::: "memory");
        __builtin_amdgcn_sched_barrier(0);

        if (j > 0) {
            // all waves done with tile j-1 (LDS reads + psum writes retired)
            asm volatile("s_waitcnt lgkmcnt(0)" ::: "memory");
            __builtin_amdgcn_s_barrier();
            // combine tile j-1 partials while others convert
            if (t < ROWS_PER_TILE) {
                float s = 0.f;
                #pragma unroll
                for (int ww = 0; ww < 8; ++ww) s += psum[ww * ROWS_PER_TILE + t];
                out[blockRow0 + (j - 1) * ROWS_PER_TILE + t] = s;
            }
        }

        // ---- convert tile j -> bf16 delta in LDS (lane l -> cols l*4..+4) ----
        #pragma unroll
        for (int q = 0; q < 4; ++q) {
            bf16x4 o;
            o[0] = (short)f2bf(xs[q][0] - fs[q][0]);
            o[1] = (short)f2bf(xs[q][1] - fs[q][1]);
            o[2] = (short)f2bf(xs[q][2] - fs[q][2]);
            o[3] = (short)f2bf(xs[q][3] - fs[q][3]);
            *(bf16x4*)(&ld[(srow + q) * LDS_STRIDE + lx4]) = o;
        }

        // ---- issue tile j+1 loads: fly across the barrier, under compute ----
        if (j + 1 < NT) {
            #pragma unroll
            for (int q = 0; q < 4; ++q) {
                const int g = (blockRow0 + (j + 1) * ROWS_PER_TILE + srow + q) * D + lx4;
                xs[q] = gload4f(x + g);
                fs[q] = gload4f(xf + g);
            }
        }

        // LDS writes visible; lgkmcnt only - prefetch stays in flight
        asm volatile("s_waitcnt lgkmcnt(0)" ::: "memory");
        __builtin_amdgcn_s_barrier();
        __builtin_amdgcn_sched_barrier(0);

        // ---- compute tile j: acc = T^T for this wave's col slice ----
        #pragma unroll
        for (int rt = 0; rt < 2; ++rt) {
            f32x4 acc0 = (f32x4){0.f, 0.f, 0.f, 0.f};
            f32x4 acc1 = (f32x4){0.f, 0.f, 0.f, 0.f};
            const unsigned short* A = &ld[(rt * 16 + lo4) * LDS_STRIDE + kg * 8];
            #pragma unroll
            for (int kb = 0; kb < 8; ++kb) {
                bf16x8 a = *(const bf16x8*)(A + kb * 32);
                // swapped operands: D[i][j] = sum_k S[slice_i][k] * delta[row_j][k]
                acc0 = __builtin_amdgcn_mfma_f32_16x16x32_bf16(b0[kb], a, acc0, 0, 0, 0);
                acc1 = __builtin_amdgcn_mfma_f32_16x16x32_bf16(b1[kb], a, acc1, 0, 0, 0);
            }
            // lane lo4 = delta row (rt*16+lo4); reg r of acc_nb holds
            // T[drow][w*32 + nb*16 + kg*4 + r] -> dot with delta at those cols
            const unsigned short* dr = &ld[(rt * 16 + lo4) * LDS_STRIDE + w * 32 + kg * 4];
            bf16x4 d0 = *(const bf16x4*)(dr);
            bf16x4 d1 = *(const bf16x4*)(dr + 16);
            float pr = 0.f;
            #pragma unroll
            for (int r = 0; r < 4; ++r) {
                pr += acc0[r] * bf2f((unsigned short)d0[r]);
                pr += acc1[r] * bf2f((unsigned short)d1[r]);
            }
            // reduce over the 4 k-groups holding the same delta row
            pr += __shfl_xor(pr, 16, 64);
            pr += __shfl_xor(pr, 32, 64);
            if (lane < 16)
                psum[w * ROWS_PER_TILE + rt * 16 + lane] = pr;
        }
    }

    // ---- final tile's combine ----
    asm volatile("s_waitcnt lgkmcnt(0)" ::: "memory");
    __builtin_amdgcn_s_barrier();
    if (t < ROWS_PER_TILE) {
        float s = 0.f;
        #pragma unroll
        for (int ww = 0; ww < 8; ++ww) s += psum[ww * ROWS_PER_TILE + t];
        out[blockRow0 + (NT - 1) * ROWS_PER_TILE + t] = s;
    }
}

extern "C" void kernel_launch(void* const* d_in, const int* in_sizes, int n_in,
                              void* d_out, int out_size, void* d_ws, size_t ws_size,
                              hipStream_t stream) {
    const float* x  = (const float*)d_in[0];
    const float* xf = (const float*)d_in[1];
    const float* S  = (const float*)d_in[2];
    float* out = (float*)d_out;
    unsigned short* Sb = (unsigned short*)d_ws;  // 65536 * 2B = 128 KB scratch

    prep_S_kernel<<<(D * D) / (256 * 4), 256, 0, stream>>>(S, Sb);

    const int nRows = in_sizes[0] / D;                      // 65536
    const int nBlocks = nRows / (NT * ROWS_PER_TILE);       // 512
    mahal_kernel<<<nBlocks, BLOCK_T, 0, stream>>>(x, xf, Sb, out);
}

// Round 11
// 33.501 us; speedup vs baseline: 1.8700x; 1.0176x over previous
//
#include <hip/hip_runtime.h>
#include <hip/hip_bf16.h>
#include <stdint.h>

// Mahalanobis: out[i] = delta_i @ S_inv @ delta_i^T, delta = x - x_fit
// N=65536, D=256.
// Round 10 -> 11: round 10 failed from a miscounted wait: with RPT=16 a tile
// is 4 load instructions/thread (not 8), so vmcnt(8) was a NO-OP and the
// convert read in-flight registers. Fix: vmcnt(4). Also reverted the fused
// S-conversion (round-7-style register over-pressure risk): prep_S kernel
// restored, S as bf16 plain loads -> AGPRs (spill-free at (512,4), proven
// rounds 8-9). This round isolates the actual hypothesis: depth-2 prefetch
// with COUNTED vmcnt kills the once-per-tile drain convoy that pins
// effective read BW at ~4.3 TB/s.

#define D 256
#define BLOCK_T 512           // 8 waves
#define RPT 16                // rows per tile
#define NT 8                  // 128 rows/block; grid = 65536/128 = 512
#define LDS_STRIDE 272

typedef __attribute__((ext_vector_type(4))) float f32x4;
typedef __attribute__((ext_vector_type(8))) short bf16x8;
typedef __attribute__((ext_vector_type(4))) short bf16x4;

static __device__ __forceinline__ unsigned short f2bf(float f) {
    union { float f; uint32_t u; } v; v.f = f;
    uint32_t u = v.u;
    return (unsigned short)((u + 0x7FFFu + ((u >> 16) & 1u)) >> 16);
}
static __device__ __forceinline__ float bf2f(unsigned short s) {
    union { uint32_t u; float f; } v; v.u = ((uint32_t)s) << 16;
    return v.f;
}

// Opaque 16B global load: fixed issue point (cannot be sunk to its use).
static __device__ __forceinline__ f32x4 gload4f(const float* p) {
    f32x4 r;
    asm volatile("global_load_dwordx4 %0, %1, off" : "=v"(r) : "v"(p));
    return r;
}

// S_inv fp32 -> bf16 (row-major; S is symmetric so this is also S^T)
__global__ void prep_S_kernel(const float* __restrict__ S, unsigned short* __restrict__ Sb) {
    int i = (blockIdx.x * 256 + threadIdx.x) * 4;
    f32x4 v = *(const f32x4*)(S + i);
    uint32_t lo = (uint32_t)f2bf(v[0]) | ((uint32_t)f2bf(v[1]) << 16);
    uint32_t hi = (uint32_t)f2bf(v[2]) | ((uint32_t)f2bf(v[3]) << 16);
    *(uint2*)(Sb + i) = make_uint2(lo, hi);
}

__global__ __launch_bounds__(BLOCK_T, 4) void mahal_kernel(
    const float* __restrict__ x, const float* __restrict__ xf,
    const unsigned short* __restrict__ Sb, float* __restrict__ out)
{
    __shared__ unsigned short ld[RPT * LDS_STRIDE]; // 8704 B
    __shared__ float psum[8 * RPT];                 // 512 B

    const int t    = threadIdx.x;
    const int w    = t >> 6;      // wave 0..7: owns S cols [w*32, w*32+32)
    const int lane = t & 63;
    const int lo4  = lane & 15;
    const int kg   = lane >> 4;   // k-group 0..3
    const int srow = t >> 5;      // staging row 0..15
    const int scol = (t & 31) * 8;
    const int blockRow0 = blockIdx.x * (NT * RPT);

    // ---- prologue: issue tiles 0 and 1 (depth-2; 4 insts each) ----
    f32x4 xs[2][2], fs[2][2];
    {
        const int g0 = (blockRow0 + srow) * D + scol;
        xs[0][0] = gload4f(x + g0);  xs[0][1] = gload4f(x + g0 + 4);
        fs[0][0] = gload4f(xf + g0); fs[0][1] = gload4f(xf + g0 + 4);
        const int g1 = (blockRow0 + RPT + srow) * D + scol;
        xs[1][0] = gload4f(x + g1);  xs[1][1] = gload4f(x + g1 + 4);
        fs[1][0] = gload4f(xf + g1); fs[1][1] = gload4f(xf + g1 + 4);
    }

    // ---- S fragments: bf16 plain loads -> AGPRs (proven rounds 8-9).
    // A-operand: A[i][k] = S[w*32 + nb*16 + i][k] (S symmetric).
    bf16x8 b0[8], b1[8];
    {
        const unsigned short* Sp = Sb + (w * 32 + lo4) * D + kg * 8;
        #pragma unroll
        for (int kb = 0; kb < 8; ++kb) {
            b0[kb] = *(const bf16x8*)(Sp + kb * 32);
            b1[kb] = *(const bf16x8*)(Sp + 16 * D + kb * 32);
        }
    }

    #pragma unroll
    for (int j = 0; j < NT; ++j) {
        const int bsel = j & 1;   // compile-time after unroll

        // counted wait: tile j's 4 insts retired; tile j+1's 4 stay in flight
        if (j < NT - 1) { asm volatile("s_waitcnt vmcnt(4)" ::: "memory"); }
        else            { asm volatile("s_waitcnt vmcnt(0)" ::: "memory"); }
        __builtin_amdgcn_sched_barrier(0);

        if (j > 0) {
            // all waves done with tile j-1 (LDS reads + psum writes retired)
            asm volatile("s_waitcnt lgkmcnt(0)" ::: "memory");
            __builtin_amdgcn_s_barrier();
            // combine tile j-1 partials while other waves convert
            if (t < RPT) {
                float s = 0.f;
                #pragma unroll
                for (int ww = 0; ww < 8; ++ww) s += psum[ww * RPT + t];
                out[blockRow0 + (j - 1) * RPT + t] = s;
            }
        }

        // ---- convert tile j -> bf16 delta in LDS ----
        {
            bf16x8 o;
            o[0] = (short)f2bf(xs[bsel][0][0] - fs[bsel][0][0]);
            o[1] = (short)f2bf(xs[bsel][0][1] - fs[bsel][0][1]);
            o[2] = (short)f2bf(xs[bsel][0][2] - fs[bsel][0][2]);
            o[3] = (short)f2bf(xs[bsel][0][3] - fs[bsel][0][3]);
            o[4] = (short)f2bf(xs[bsel][1][0] - fs[bsel][1][0]);
            o[5] = (short)f2bf(xs[bsel][1][1] - fs[bsel][1][1]);
            o[6] = (short)f2bf(xs[bsel][1][2] - fs[bsel][1][2]);
            o[7] = (short)f2bf(xs[bsel][1][3] - fs[bsel][1][3]);
            *(bf16x8*)(&ld[srow * LDS_STRIDE + scol]) = o;
        }

        // ---- re-stage this buffer with tile j+2 (same parity) ----
        if (j + 2 < NT) {
            const int g = (blockRow0 + (j + 2) * RPT + srow) * D + scol;
            xs[bsel][0] = gload4f(x + g);  xs[bsel][1] = gload4f(x + g + 4);
            fs[bsel][0] = gload4f(xf + g); fs[bsel][1] = gload4f(xf + g + 4);
        }

        // LDS writes visible; lgkmcnt only - prefetch stays in flight
        asm volatile("s_waitcnt lgkmcnt(0)" ::: "memory");
        __builtin_amdgcn_s_barrier();
        __builtin_amdgcn_sched_barrier(0);

        // ---- compute tile j: T^T for this wave's 32-col slice ----
        {
            f32x4 acc0 = (f32x4){0.f, 0.f, 0.f, 0.f};
            f32x4 acc1 = (f32x4){0.f, 0.f, 0.f, 0.f};
            const unsigned short* A = &ld[lo4 * LDS_STRIDE + kg * 8];
            #pragma unroll
            for (int kb = 0; kb < 8; ++kb) {
                bf16x8 a = *(const bf16x8*)(A + kb * 32);
                // swapped operands: D[i][r] = sum_k S[slice_i][k]*delta[row_r][k]
                acc0 = __builtin_amdgcn_mfma_f32_16x16x32_bf16(b0[kb], a, acc0, 0, 0, 0);
                acc1 = __builtin_amdgcn_mfma_f32_16x16x32_bf16(b1[kb], a, acc1, 0, 0, 0);
            }
            // lane lo4 = delta row; reg r of acc_nb = T[drow][w*32+nb*16+kg*4+r]
            const unsigned short* dr = &ld[lo4 * LDS_STRIDE + w * 32 + kg * 4];
            bf16x4 d0 = *(const bf16x4*)(dr);
            bf16x4 d1 = *(const bf16x4*)(dr + 16);
            float pr = 0.f;
            #pragma unroll
            for (int r = 0; r < 4; ++r) {
                pr += acc0[r] * bf2f((unsigned short)d0[r]);
                pr += acc1[r] * bf2f((unsigned short)d1[r]);
            }
            // reduce over the 4 k-groups holding the same delta row
            pr += __shfl_xor(pr, 16, 64);
            pr += __shfl_xor(pr, 32, 64);
            if (lane < 16)
                psum[w * RPT + lane] = pr;
        }
    }

    // ---- final tile's combine ----
    asm volatile("s_waitcnt lgkmcnt(0)" ::: "memory");
    __builtin_amdgcn_s_barrier();
    if (t < RPT) {
        float s = 0.f;
        #pragma unroll
        for (int ww = 0; ww < 8; ++ww) s += psum[ww * RPT + t];
        out[blockRow0 + (NT - 1) * RPT + t] = s;
    }
}

extern "C" void kernel_launch(void* const* d_in, const int* in_sizes, int n_in,
                              void* d_out, int out_size, void* d_ws, size_t ws_size,
                              hipStream_t stream) {
    const float* x  = (const float*)d_in[0];
    const float* xf = (const float*)d_in[1];
    const float* S  = (const float*)d_in[2];
    float* out = (float*)d_out;
    unsigned short* Sb = (unsigned short*)d_ws;  // 65536 * 2B = 128 KB scratch

    prep_S_kernel<<<(D * D) / (256 * 4), 256, 0, stream>>>(S, Sb);

    const int nRows = in_sizes[0] / D;                 // 65536
    const int nBlocks = nRows / (NT * RPT);            // 512
    mahal_kernel<<<nBlocks, BLOCK_T, 0, stream>>>(x, xf, Sb, out);
}